// Round 2
// baseline (653.057 us; speedup 1.0000x reference)
//
#include <hip/hip_runtime.h>
#include <hip/hip_bf16.h>

#define NROWS 16384
#define DIM 128
#define TAU_INV 14.285714285714285714f
#define K1_CONST 20.6099273650808706f /* log2(e)/tau */

typedef __attribute__((ext_vector_type(8))) __bf16 bf16x8;
typedef __attribute__((ext_vector_type(4))) float f32x4;
typedef unsigned int u32;
typedef unsigned short u16;

#if __has_builtin(__builtin_amdgcn_exp2f)
#define EXP2F(x) __builtin_amdgcn_exp2f(x)
#else
#define EXP2F(x) exp2f(x)
#endif

__device__ __forceinline__ u16 f2bf(float x) {
  __hip_bfloat16 h = __float2bfloat16(x);
  return *reinterpret_cast<u16*>(&h);
}

__device__ __forceinline__ void gload_lds16(const void* g, void* l) {
  __builtin_amdgcn_global_load_lds(
      (const __attribute__((address_space(1))) u32*)g,
      (__attribute__((address_space(3))) u32*)l, 16, 0, 0);
}

// ---------------- Kernel A: row L2-normalize -> bf16, pos_sim (fp32) -------
__global__ __launch_bounds__(256) void nrm_kernel(
    const float* __restrict__ z1, const float* __restrict__ z2,
    u16* __restrict__ z1n, u16* __restrict__ z2n, float* __restrict__ pos_sim)
{
  const int tid  = threadIdx.x;
  const int lane = tid & 63, wid = tid >> 6;
  const int row  = blockIdx.x * 4 + wid;
  const float2 a = *(const float2*)(z1 + (size_t)row * DIM + lane * 2);
  const float2 b = *(const float2*)(z2 + (size_t)row * DIM + lane * 2);
  float ss1 = a.x * a.x + a.y * a.y;
  float ss2 = b.x * b.x + b.y * b.y;
  float dd  = a.x * b.x + a.y * b.y;
#pragma unroll
  for (int d = 1; d < 64; d <<= 1) {
    ss1 += __shfl_xor(ss1, d);
    ss2 += __shfl_xor(ss2, d);
    dd  += __shfl_xor(dd,  d);
  }
  const float inv1 = 1.0f / fmaxf(sqrtf(ss1), 1e-12f);
  const float inv2 = 1.0f / fmaxf(sqrtf(ss2), 1e-12f);
  u32 p1 = (u32)f2bf(a.x * inv1) | ((u32)f2bf(a.y * inv1) << 16);
  u32 p2 = (u32)f2bf(b.x * inv2) | ((u32)f2bf(b.y * inv2) << 16);
  ((u32*)z1n)[(size_t)row * (DIM / 2) + lane] = p1;
  ((u32*)z2n)[(size_t)row * (DIM / 2) + lane] = p2;
  if (lane == 0) pos_sim[row] = dd * inv1 * inv2 * TAU_INV;
}

// ---------------- Kernel B: fused GEMM + fixed-max sum-exp ------------------
// grid = 1024 : rb = bx&63 (256 q-rows), ch = bx>>6 (16 chunks of 2048 cols)
// concat columns: ch<8 -> z2n (cross view), ch>=8 -> z1n (intra, diag masked)
// 4 waves/block; each wave owns 64 q-rows (4 groups of 16), G=4 reuse of A-frag.
__global__ __launch_bounds__(256, 4) void lse_kernel(
    const u16* __restrict__ z1n, const u16* __restrict__ z2n,
    float* __restrict__ lparts)
{
  __shared__ __attribute__((aligned(16))) char smem[32768]; // 2 x 64x128 bf16
  const int tid    = threadIdx.x;
  const int lane   = tid & 63, wid = tid >> 6;
  const int rb     = blockIdx.x & 63, ch = blockIdx.x >> 6;
  const int lane15 = lane & 15, laneHi = lane >> 4, lane7 = lane & 7;
  const int qb     = rb * 256 + wid * 64; // this wave's first q-row

  // Q fragments (B-operand), register-resident: 4 q-groups x 4 k-slices
  bf16x8 qf[4][4];
#pragma unroll
  for (int qg = 0; qg < 4; ++qg)
#pragma unroll
    for (int ks = 0; ks < 4; ++ks)
      qf[qg][ks] = *(const bf16x8*)(z1n + (size_t)(qb + qg * 16 + lane15) * DIM +
                                    ks * 32 + laneHi * 8);

  // column source for this chunk (wave-uniform constant)
  const u16* zt = (ch < 8) ? (z2n + (size_t)ch * 2048 * DIM)
                           : (z1n + (size_t)(ch - 8) * 2048 * DIM);
  int t_diag = -1;
  if (ch >= 8) {
    const int dbase = qb - (ch - 8) * 2048;
    if (dbase >= 0 && dbase < 2048) t_diag = dbase >> 6;
  }

  // staging: LDS linear, global source pre-swizzled (chunk ^= row&7)
  const int gchunk = (tid & 15) ^ ((tid >> 4) & 7);
  const char* const src0 = (const char*)zt + (((tid >> 4) << 8) + (gchunk << 4));
  char* const dst0 = smem + (wid << 10);

  float lacc[4][4] = {};

  auto stage = [&](int t, int cur) {
    const char* s = src0 + (size_t)t * 16384;
    char* d = dst0 + cur * 16384;
#pragma unroll
    for (int i = 0; i < 4; ++i)
      gload_lds16(s + (i << 12), d + (i << 12));
  };

  auto compute = [&](int cur, bool dtile) {
    const char* buf = smem + cur * 16384;
#pragma unroll
    for (int kb = 0; kb < 4; ++kb) {
      const int rowb = (kb * 16 + lane15) * 256;
      bf16x8 af[4];
#pragma unroll
      for (int ks = 0; ks < 4; ++ks)
        af[ks] = *(const bf16x8*)(buf + rowb + ((((ks << 2) + laneHi) ^ lane7) << 4));
      f32x4 acc[4] = {{0.f,0.f,0.f,0.f},{0.f,0.f,0.f,0.f},
                      {0.f,0.f,0.f,0.f},{0.f,0.f,0.f,0.f}};
#pragma unroll
      for (int ks = 0; ks < 4; ++ks)
#pragma unroll
        for (int qg = 0; qg < 4; ++qg)
          acc[qg] = __builtin_amdgcn_mfma_f32_16x16x32_bf16(af[ks], qf[qg][ks],
                                                            acc[qg], 0, 0, 0);
      if (!dtile) {
#pragma unroll
        for (int qg = 0; qg < 4; ++qg)
#pragma unroll
          for (int j = 0; j < 4; ++j)
            lacc[qg][j] += EXP2F(fmaf(acc[qg][j], K1_CONST, -K1_CONST));
      } else {
#pragma unroll
        for (int qg = 0; qg < 4; ++qg)
#pragma unroll
          for (int j = 0; j < 4; ++j) {
            float v = EXP2F(fmaf(acc[qg][j], K1_CONST, -K1_CONST));
            if (kb == qg && (laneHi * 4 + j) == lane15) v = 0.0f;
            lacc[qg][j] += v;
          }
      }
    }
  };

  stage(0, 0);
  __syncthreads();
  int cur = 0;
#pragma unroll 1
  for (int t = 0; t < 32; ++t) {
    if (t + 1 < 32) stage(t + 1, cur ^ 1);
    compute(cur, t == t_diag);
    __syncthreads();
    cur ^= 1;
  }

  // reduce 4 k-partitions (laneHi) per q-row, write partials
#pragma unroll
  for (int qg = 0; qg < 4; ++qg) {
    float l = (lacc[qg][0] + lacc[qg][1]) + (lacc[qg][2] + lacc[qg][3]);
    l += __shfl_xor(l, 16);
    l += __shfl_xor(l, 32);
    if (lane < 16)
      lparts[(size_t)ch * NROWS + qb + qg * 16 + lane15] = l;
  }
}

// ---------------- Kernel C: finalize (32 blocks, atomic into out) ----------
__global__ __launch_bounds__(256) void fin_kernel(
    const float* __restrict__ lparts, const float* __restrict__ pos,
    float* __restrict__ out)
{
  __shared__ float red[4];
  const int tid = threadIdx.x, bx = blockIdx.x;
  float s = 0.f;
#pragma unroll 1
  for (int i = bx * 512 + tid; i < (bx + 1) * 512; i += 256) {
    float l = 0.f;
#pragma unroll
    for (int c = 0; c < 16; ++c) l += lparts[(size_t)c * NROWS + i];
    s += logf(l) - pos[i];
  }
#pragma unroll
  for (int d = 1; d < 64; d <<= 1) s += __shfl_xor(s, d);
  if ((tid & 63) == 0) red[tid >> 6] = s;
  __syncthreads();
  if (tid == 0) {
    float t = (red[0] + red[1]) + (red[2] + red[3]);
    float v = t / (float)NROWS;
    if (bx == 0) v += TAU_INV; // mean(lse) includes the fixed max 1/tau
    atomicAdd(out, v);
  }
}

extern "C" void kernel_launch(void* const* d_in, const int* in_sizes, int n_in,
                              void* d_out, int out_size, void* d_ws, size_t ws_size,
                              hipStream_t stream) {
  const float* z1 = (const float*)d_in[0];
  const float* z2 = (const float*)d_in[1];
  float* out = (float*)d_out;
  char* ws = (char*)d_ws;
  u16* z1n = (u16*)ws;                                         // 4 MB
  u16* z2n = (u16*)(ws + (size_t)NROWS * DIM * 2);             // 4 MB
  float* pos = (float*)(ws + (size_t)NROWS * DIM * 4);         // 64 KB
  float* lparts = (float*)(ws + (size_t)NROWS * DIM * 4 + (size_t)NROWS * 4); // 1 MB

  hipMemsetAsync(d_out, 0, sizeof(float), stream);
  hipLaunchKernelGGL(nrm_kernel, dim3(NROWS / 4), dim3(256), 0, stream,
                     z1, z2, z1n, z2n, pos);
  hipLaunchKernelGGL(lse_kernel, dim3(1024), dim3(256), 0, stream,
                     z1n, z2n, lparts);
  hipLaunchKernelGGL(fin_kernel, dim3(32), dim3(256), 0, stream,
                     lparts, pos, out);
}

// Round 3
// 194.324 us; speedup vs baseline: 3.3607x; 3.3607x over previous
//
#include <hip/hip_runtime.h>
#include <hip/hip_bf16.h>

#define NROWS 16384
#define DIM 128
#define TAU_INV 14.285714285714285714f
#define K1_CONST 20.6099273650808706f /* log2(e)/tau */

typedef __attribute__((ext_vector_type(8))) __bf16 bf16x8;
typedef __attribute__((ext_vector_type(4))) float f32x4;
typedef unsigned int u32;
typedef unsigned short u16;

#if __has_builtin(__builtin_amdgcn_exp2f)
#define EXP2F(x) __builtin_amdgcn_exp2f(x)
#else
#define EXP2F(x) exp2f(x)
#endif

__device__ __forceinline__ u16 f2bf(float x) {
  __hip_bfloat16 h = __float2bfloat16(x);
  return *reinterpret_cast<u16*>(&h);
}

__device__ __forceinline__ void gload_lds16(const void* g, void* l) {
  __builtin_amdgcn_global_load_lds(
      (const __attribute__((address_space(1))) u32*)g,
      (__attribute__((address_space(3))) u32*)l, 16, 0, 0);
}

// ---------------- Kernel A: row L2-normalize -> bf16, pos_sim (fp32) -------
__global__ __launch_bounds__(256) void nrm_kernel(
    const float* __restrict__ z1, const float* __restrict__ z2,
    u16* __restrict__ z1n, u16* __restrict__ z2n, float* __restrict__ pos_sim)
{
  const int tid  = threadIdx.x;
  const int lane = tid & 63, wid = tid >> 6;
  const int row  = blockIdx.x * 4 + wid;
  const float2 a = *(const float2*)(z1 + (size_t)row * DIM + lane * 2);
  const float2 b = *(const float2*)(z2 + (size_t)row * DIM + lane * 2);
  float ss1 = a.x * a.x + a.y * a.y;
  float ss2 = b.x * b.x + b.y * b.y;
  float dd  = a.x * b.x + a.y * b.y;
#pragma unroll
  for (int d = 1; d < 64; d <<= 1) {
    ss1 += __shfl_xor(ss1, d);
    ss2 += __shfl_xor(ss2, d);
    dd  += __shfl_xor(dd,  d);
  }
  const float inv1 = 1.0f / fmaxf(sqrtf(ss1), 1e-12f);
  const float inv2 = 1.0f / fmaxf(sqrtf(ss2), 1e-12f);
  u32 p1 = (u32)f2bf(a.x * inv1) | ((u32)f2bf(a.y * inv1) << 16);
  u32 p2 = (u32)f2bf(b.x * inv2) | ((u32)f2bf(b.y * inv2) << 16);
  ((u32*)z1n)[(size_t)row * (DIM / 2) + lane] = p1;
  ((u32*)z2n)[(size_t)row * (DIM / 2) + lane] = p2;
  if (lane == 0) pos_sim[row] = dd * inv1 * inv2 * TAU_INV;
}

// ---------------- Kernel B: fused GEMM + fixed-max sum-exp ------------------
// grid = 1024 : rb = bx&63 (256 q-rows), ch = bx>>6 (16 chunks of 2048 cols)
// concat columns: ch<8 -> z2n (cross view), ch>=8 -> z1n (intra, diag masked)
// 4 waves/block; each wave owns 64 q-rows (4 groups of 16), G=4 reuse of A-frag.
// launch_bounds min-waves=2 -> 256-VGPR cap: qf[4][4] (64 VGPR) MUST stay in
// registers; (256,4) in round 2 forced spills -> 1.85 GB scratch traffic.
__global__ __launch_bounds__(256, 2) void lse_kernel(
    const u16* __restrict__ z1n, const u16* __restrict__ z2n,
    float* __restrict__ lparts)
{
  __shared__ __attribute__((aligned(16))) char smem[32768]; // 2 x 64x128 bf16
  const int tid    = threadIdx.x;
  const int lane   = tid & 63, wid = tid >> 6;
  const int rb     = blockIdx.x & 63, ch = blockIdx.x >> 6;
  const int lane15 = lane & 15, laneHi = lane >> 4, lane7 = lane & 7;
  const int qb     = rb * 256 + wid * 64; // this wave's first q-row

  // Q fragments (B-operand), register-resident: 4 q-groups x 4 k-slices
  bf16x8 qf[4][4];
#pragma unroll
  for (int qg = 0; qg < 4; ++qg)
#pragma unroll
    for (int ks = 0; ks < 4; ++ks)
      qf[qg][ks] = *(const bf16x8*)(z1n + (size_t)(qb + qg * 16 + lane15) * DIM +
                                    ks * 32 + laneHi * 8);

  // column source for this chunk (wave-uniform constant)
  const u16* zt = (ch < 8) ? (z2n + (size_t)ch * 2048 * DIM)
                           : (z1n + (size_t)(ch - 8) * 2048 * DIM);
  int t_diag = -1;
  if (ch >= 8) {
    const int dbase = qb - (ch - 8) * 2048;
    if (dbase >= 0 && dbase < 2048) t_diag = dbase >> 6;
  }

  // staging: LDS linear, global source pre-swizzled (chunk ^= row&7)
  const int gchunk = (tid & 15) ^ ((tid >> 4) & 7);
  const char* const src0 = (const char*)zt + (((tid >> 4) << 8) + (gchunk << 4));
  char* const dst0 = smem + (wid << 10);

  float lacc[4][4] = {};

  auto stage = [&](int t, int cur) {
    const char* s = src0 + (size_t)t * 16384;
    char* d = dst0 + cur * 16384;
#pragma unroll
    for (int i = 0; i < 4; ++i)
      gload_lds16(s + (i << 12), d + (i << 12));
  };

  auto compute = [&](int cur, bool dtile) {
    const char* buf = smem + cur * 16384;
#pragma unroll
    for (int kb = 0; kb < 4; ++kb) {
      const int rowb = (kb * 16 + lane15) * 256;
      bf16x8 af[4];
#pragma unroll
      for (int ks = 0; ks < 4; ++ks)
        af[ks] = *(const bf16x8*)(buf + rowb + ((((ks << 2) + laneHi) ^ lane7) << 4));
      f32x4 acc[4] = {{0.f,0.f,0.f,0.f},{0.f,0.f,0.f,0.f},
                      {0.f,0.f,0.f,0.f},{0.f,0.f,0.f,0.f}};
#pragma unroll
      for (int ks = 0; ks < 4; ++ks)
#pragma unroll
        for (int qg = 0; qg < 4; ++qg)
          acc[qg] = __builtin_amdgcn_mfma_f32_16x16x32_bf16(af[ks], qf[qg][ks],
                                                            acc[qg], 0, 0, 0);
      if (!dtile) {
#pragma unroll
        for (int qg = 0; qg < 4; ++qg)
#pragma unroll
          for (int j = 0; j < 4; ++j)
            lacc[qg][j] += EXP2F(fmaf(acc[qg][j], K1_CONST, -K1_CONST));
      } else {
#pragma unroll
        for (int qg = 0; qg < 4; ++qg)
#pragma unroll
          for (int j = 0; j < 4; ++j) {
            float v = EXP2F(fmaf(acc[qg][j], K1_CONST, -K1_CONST));
            if (kb == qg && (laneHi * 4 + j) == lane15) v = 0.0f;
            lacc[qg][j] += v;
          }
      }
    }
  };

  stage(0, 0);
  __syncthreads();
  int cur = 0;
#pragma unroll 1
  for (int t = 0; t < 32; ++t) {
    if (t + 1 < 32) stage(t + 1, cur ^ 1);
    compute(cur, t == t_diag);
    __syncthreads();
    cur ^= 1;
  }

  // reduce 4 k-partitions (laneHi) per q-row, write partials
#pragma unroll
  for (int qg = 0; qg < 4; ++qg) {
    float l = (lacc[qg][0] + lacc[qg][1]) + (lacc[qg][2] + lacc[qg][3]);
    l += __shfl_xor(l, 16);
    l += __shfl_xor(l, 32);
    if (lane < 16)
      lparts[(size_t)ch * NROWS + qb + qg * 16 + lane15] = l;
  }
}

// ---------------- Kernel C: finalize (32 blocks, atomic into out) ----------
__global__ __launch_bounds__(256) void fin_kernel(
    const float* __restrict__ lparts, const float* __restrict__ pos,
    float* __restrict__ out)
{
  __shared__ float red[4];
  const int tid = threadIdx.x, bx = blockIdx.x;
  float s = 0.f;
#pragma unroll 1
  for (int i = bx * 512 + tid; i < (bx + 1) * 512; i += 256) {
    float l = 0.f;
#pragma unroll
    for (int c = 0; c < 16; ++c) l += lparts[(size_t)c * NROWS + i];
    s += logf(l) - pos[i];
  }
#pragma unroll
  for (int d = 1; d < 64; d <<= 1) s += __shfl_xor(s, d);
  if ((tid & 63) == 0) red[tid >> 6] = s;
  __syncthreads();
  if (tid == 0) {
    float t = (red[0] + red[1]) + (red[2] + red[3]);
    float v = t / (float)NROWS;
    if (bx == 0) v += TAU_INV; // mean(lse) includes the fixed max 1/tau
    atomicAdd(out, v);
  }
}

extern "C" void kernel_launch(void* const* d_in, const int* in_sizes, int n_in,
                              void* d_out, int out_size, void* d_ws, size_t ws_size,
                              hipStream_t stream) {
  const float* z1 = (const float*)d_in[0];
  const float* z2 = (const float*)d_in[1];
  float* out = (float*)d_out;
  char* ws = (char*)d_ws;
  u16* z1n = (u16*)ws;                                         // 4 MB
  u16* z2n = (u16*)(ws + (size_t)NROWS * DIM * 2);             // 4 MB
  float* pos = (float*)(ws + (size_t)NROWS * DIM * 4);         // 64 KB
  float* lparts = (float*)(ws + (size_t)NROWS * DIM * 4 + (size_t)NROWS * 4); // 1 MB

  hipMemsetAsync(d_out, 0, sizeof(float), stream);
  hipLaunchKernelGGL(nrm_kernel, dim3(NROWS / 4), dim3(256), 0, stream,
                     z1, z2, z1n, z2n, pos);
  hipLaunchKernelGGL(lse_kernel, dim3(1024), dim3(256), 0, stream,
                     z1n, z2n, lparts);
  hipLaunchKernelGGL(fin_kernel, dim3(32), dim3(256), 0, stream,
                     lparts, pos, out);
}

// Round 4
// 193.145 us; speedup vs baseline: 3.3812x; 1.0061x over previous
//
#include <hip/hip_runtime.h>
#include <hip/hip_bf16.h>

#define NROWS 16384
#define DIM 128
#define TAU_INV 14.285714285714285714f
#define K1_CONST 20.6099273650808706f /* log2(e)/tau ; exp(cos/tau) = 2^(K1*cos) */

typedef __attribute__((ext_vector_type(8))) __bf16 bf16x8;
typedef __attribute__((ext_vector_type(4))) float f32x4;
typedef unsigned int u32;
typedef unsigned short u16;

#if __has_builtin(__builtin_amdgcn_exp2f)
#define EXP2F(x) __builtin_amdgcn_exp2f(x)
#else
#define EXP2F(x) exp2f(x)
#endif

__device__ __forceinline__ u16 f2bf(float x) {
  __hip_bfloat16 h = __float2bfloat16(x);
  return *reinterpret_cast<u16*>(&h);
}

__device__ __forceinline__ void gload_lds16(const void* g, void* l) {
  __builtin_amdgcn_global_load_lds(
      (const __attribute__((address_space(1))) u32*)g,
      (__attribute__((address_space(3))) u32*)l, 16, 0, 0);
}

// ------- Kernel A: normalize -> z1q (K1-scaled Q), z1c/z2c (unit), pos -----
__global__ __launch_bounds__(256) void nrm_kernel(
    const float* __restrict__ z1, const float* __restrict__ z2,
    u16* __restrict__ z1q, u16* __restrict__ z1c, u16* __restrict__ z2c,
    float* __restrict__ pos_sim)
{
  const int tid  = threadIdx.x;
  const int lane = tid & 63, wid = tid >> 6;
  const int row  = blockIdx.x * 4 + wid;
  const float2 a = *(const float2*)(z1 + (size_t)row * DIM + lane * 2);
  const float2 b = *(const float2*)(z2 + (size_t)row * DIM + lane * 2);
  float ss1 = a.x * a.x + a.y * a.y;
  float ss2 = b.x * b.x + b.y * b.y;
  float dd  = a.x * b.x + a.y * b.y;
#pragma unroll
  for (int d = 1; d < 64; d <<= 1) {
    ss1 += __shfl_xor(ss1, d);
    ss2 += __shfl_xor(ss2, d);
    dd  += __shfl_xor(dd,  d);
  }
  const float inv1 = 1.0f / fmaxf(sqrtf(ss1), 1e-12f);
  const float inv2 = 1.0f / fmaxf(sqrtf(ss2), 1e-12f);
  const float s1q = inv1 * K1_CONST;
  u32 pq = (u32)f2bf(a.x * s1q) | ((u32)f2bf(a.y * s1q) << 16);
  u32 p1 = (u32)f2bf(a.x * inv1) | ((u32)f2bf(a.y * inv1) << 16);
  u32 p2 = (u32)f2bf(b.x * inv2) | ((u32)f2bf(b.y * inv2) << 16);
  ((u32*)z1q)[(size_t)row * (DIM / 2) + lane] = pq;
  ((u32*)z1c)[(size_t)row * (DIM / 2) + lane] = p1;
  ((u32*)z2c)[(size_t)row * (DIM / 2) + lane] = p2;
  if (lane == 0) pos_sim[row] = dd * inv1 * inv2 * TAU_INV;
}

// ---------------- Kernel B: fused GEMM + sum(2^score) ----------------------
// grid = 1024 : rb = bx&63 (256 q-rows), ch = bx>>6 (16 chunks of 2048 cols)
// ch<8 -> z2c (cross view), ch>=8 -> z1c (intra, diag masked)
// 4 waves/block, each wave: 64 q-rows (4 groups of 16), G=4 A-frag reuse.
// launch_bounds(256,3): target <=170 unified VGPR+AGPR -> 3 waves/SIMD.
// (256,4)=128-cap spilled qf (round 2, 1.85GB scratch); (256,2) gave 2 waves.
__global__ __launch_bounds__(256, 3) void lse_kernel(
    const u16* __restrict__ z1q, const u16* __restrict__ z1c,
    const u16* __restrict__ z2c, float* __restrict__ lparts)
{
  __shared__ __attribute__((aligned(16))) char smem[32768]; // 2 x 64x128 bf16
  const int tid    = threadIdx.x;
  const int lane   = tid & 63, wid = tid >> 6;
  const int rb     = blockIdx.x & 63, ch = blockIdx.x >> 6;
  const int lane15 = lane & 15, laneHi = lane >> 4;
  const int qb     = rb * 256 + wid * 64; // this wave's first q-row

  // Q fragments (B-operand), K1-pre-scaled, register-resident
  bf16x8 qf[4][4];
#pragma unroll
  for (int qg = 0; qg < 4; ++qg)
#pragma unroll
    for (int ks = 0; ks < 4; ++ks)
      qf[qg][ks] = *(const bf16x8*)(z1q + (size_t)(qb + qg * 16 + lane15) * DIM +
                                    ks * 32 + laneHi * 8);

  // column source for this chunk (wave-uniform constant)
  const u16* zt = (ch < 8) ? (z2c + (size_t)ch * 2048 * DIM)
                           : (z1c + (size_t)(ch - 8) * 2048 * DIM);
  int t_diag = -1;
  if (ch >= 8) {
    const int dbase = qb - (ch - 8) * 2048;
    if (dbase >= 0 && dbase < 2048) t_diag = dbase >> 6;
  }

  // staging: LDS linear, global source pre-swizzled with 4-bit row rotation
  // LDS[r][p] holds global[r][p ^ (r&15)] (16B chunks) -> conflict-free reads
  const int gchunk = (tid & 15) ^ ((tid >> 4) & 15);
  const char* const src0 = (const char*)zt + (((tid >> 4) << 8) + (gchunk << 4));
  char* const dst0 = smem + (wid << 10);

  float lacc[4][4] = {};

  auto stage = [&](int t, int cur) {
    const char* s = src0 + (size_t)t * 16384;
    char* d = dst0 + cur * 16384;
#pragma unroll
    for (int i = 0; i < 4; ++i)
      gload_lds16(s + (i << 12), d + (i << 12));
  };

  auto compute = [&](int cur, bool dtile) {
    const char* buf = smem + cur * 16384;
#pragma unroll
    for (int kb = 0; kb < 4; ++kb) {
      const int rowb = (kb * 16 + lane15) * 256;
      bf16x8 af[4];
#pragma unroll
      for (int ks = 0; ks < 4; ++ks)
        af[ks] = *(const bf16x8*)(buf + rowb + ((((ks << 2) + laneHi) ^ lane15) << 4));
      f32x4 acc[4] = {{0.f,0.f,0.f,0.f},{0.f,0.f,0.f,0.f},
                      {0.f,0.f,0.f,0.f},{0.f,0.f,0.f,0.f}};
      __builtin_amdgcn_s_setprio(1);
#pragma unroll
      for (int ks = 0; ks < 4; ++ks)
#pragma unroll
        for (int qg = 0; qg < 4; ++qg)
          acc[qg] = __builtin_amdgcn_mfma_f32_16x16x32_bf16(af[ks], qf[qg][ks],
                                                            acc[qg], 0, 0, 0);
      __builtin_amdgcn_s_setprio(0);
      if (!dtile) {
#pragma unroll
        for (int qg = 0; qg < 4; ++qg)
#pragma unroll
          for (int j = 0; j < 4; ++j)
            lacc[qg][j] += EXP2F(acc[qg][j]);
      } else {
#pragma unroll
        for (int qg = 0; qg < 4; ++qg)
#pragma unroll
          for (int j = 0; j < 4; ++j) {
            float v = EXP2F(acc[qg][j]);
            if (kb == qg && (laneHi * 4 + j) == lane15) v = 0.0f;
            lacc[qg][j] += v;
          }
      }
    }
  };

  stage(0, 0);
  __syncthreads();
  int cur = 0;
#pragma unroll 1
  for (int t = 0; t < 32; ++t) {
    if (t + 1 < 32) stage(t + 1, cur ^ 1);
    compute(cur, t == t_diag);
    __syncthreads();
    cur ^= 1;
  }

  // reduce 4 k-partitions (laneHi) per q-row, write partials
#pragma unroll
  for (int qg = 0; qg < 4; ++qg) {
    float l = (lacc[qg][0] + lacc[qg][1]) + (lacc[qg][2] + lacc[qg][3]);
    l += __shfl_xor(l, 16);
    l += __shfl_xor(l, 32);
    if (lane < 16)
      lparts[(size_t)ch * NROWS + qb + qg * 16 + lane15] = l;
  }
}

// ---------------- Kernel C: finalize (32 blocks, atomic into out) ----------
// P_i = sum 2^(K1*cos) = sum exp(s_i) exactly -> lse = ln(P_i), no bias term
__global__ __launch_bounds__(256) void fin_kernel(
    const float* __restrict__ lparts, const float* __restrict__ pos,
    float* __restrict__ out)
{
  __shared__ float red[4];
  const int tid = threadIdx.x, bx = blockIdx.x;
  float s = 0.f;
#pragma unroll 1
  for (int i = bx * 512 + tid; i < (bx + 1) * 512; i += 256) {
    float l = 0.f;
#pragma unroll
    for (int c = 0; c < 16; ++c) l += lparts[(size_t)c * NROWS + i];
    s += logf(l) - pos[i];
  }
#pragma unroll
  for (int d = 1; d < 64; d <<= 1) s += __shfl_xor(s, d);
  if ((tid & 63) == 0) red[tid >> 6] = s;
  __syncthreads();
  if (tid == 0) {
    float t = (red[0] + red[1]) + (red[2] + red[3]);
    atomicAdd(out, t / (float)NROWS);
  }
}

extern "C" void kernel_launch(void* const* d_in, const int* in_sizes, int n_in,
                              void* d_out, int out_size, void* d_ws, size_t ws_size,
                              hipStream_t stream) {
  const float* z1 = (const float*)d_in[0];
  const float* z2 = (const float*)d_in[1];
  float* out = (float*)d_out;
  char* ws = (char*)d_ws;
  const size_t MB4 = (size_t)NROWS * DIM * 2;
  u16* z1q = (u16*)ws;                        // 4 MB (K1-scaled Q)
  u16* z1c = (u16*)(ws + MB4);                // 4 MB (unit, intra cols)
  u16* z2c = (u16*)(ws + 2 * MB4);            // 4 MB (unit, cross cols)
  float* pos = (float*)(ws + 3 * MB4);        // 64 KB
  float* lparts = (float*)(ws + 3 * MB4 + (size_t)NROWS * 4); // 1 MB

  hipMemsetAsync(d_out, 0, sizeof(float), stream);
  hipLaunchKernelGGL(nrm_kernel, dim3(NROWS / 4), dim3(256), 0, stream,
                     z1, z2, z1q, z1c, z2c, pos);
  hipLaunchKernelGGL(lse_kernel, dim3(1024), dim3(256), 0, stream,
                     z1q, z1c, z2c, lparts);
  hipLaunchKernelGGL(fin_kernel, dim3(32), dim3(256), 0, stream,
                     lparts, pos, out);
}

// Round 5
// 185.570 us; speedup vs baseline: 3.5192x; 1.0408x over previous
//
#include <hip/hip_runtime.h>
#include <hip/hip_bf16.h>

#define NROWS 16384
#define DIM 128
#define TAU_INV 14.285714285714285714f
#define K1_CONST 20.6099273650808706f /* log2(e)/tau ; exp(cos/tau) = 2^(K1*cos) */

typedef __attribute__((ext_vector_type(8))) __bf16 bf16x8;
typedef __attribute__((ext_vector_type(4))) float f32x4;
typedef unsigned int u32;
typedef unsigned short u16;

#if __has_builtin(__builtin_amdgcn_exp2f)
#define EXP2F(x) __builtin_amdgcn_exp2f(x)
#else
#define EXP2F(x) exp2f(x)
#endif

__device__ __forceinline__ u16 f2bf(float x) {
  __hip_bfloat16 h = __float2bfloat16(x);
  return *reinterpret_cast<u16*>(&h);
}

__device__ __forceinline__ void gload_lds16(const void* g, void* l) {
  __builtin_amdgcn_global_load_lds(
      (const __attribute__((address_space(1))) u32*)g,
      (__attribute__((address_space(3))) u32*)l, 16, 0, 0);
}

// ------- Kernel A: normalize -> z1q (K1-scaled Q), z1c/z2c (unit), pos -----
__global__ __launch_bounds__(256) void nrm_kernel(
    const float* __restrict__ z1, const float* __restrict__ z2,
    u16* __restrict__ z1q, u16* __restrict__ z1c, u16* __restrict__ z2c,
    float* __restrict__ pos_sim)
{
  const int tid  = threadIdx.x;
  const int lane = tid & 63, wid = tid >> 6;
  const int row  = blockIdx.x * 4 + wid;
  const float2 a = *(const float2*)(z1 + (size_t)row * DIM + lane * 2);
  const float2 b = *(const float2*)(z2 + (size_t)row * DIM + lane * 2);
  float ss1 = a.x * a.x + a.y * a.y;
  float ss2 = b.x * b.x + b.y * b.y;
  float dd  = a.x * b.x + a.y * b.y;
#pragma unroll
  for (int d = 1; d < 64; d <<= 1) {
    ss1 += __shfl_xor(ss1, d);
    ss2 += __shfl_xor(ss2, d);
    dd  += __shfl_xor(dd,  d);
  }
  const float inv1 = 1.0f / fmaxf(sqrtf(ss1), 1e-12f);
  const float inv2 = 1.0f / fmaxf(sqrtf(ss2), 1e-12f);
  const float s1q = inv1 * K1_CONST;
  u32 pq = (u32)f2bf(a.x * s1q) | ((u32)f2bf(a.y * s1q) << 16);
  u32 p1 = (u32)f2bf(a.x * inv1) | ((u32)f2bf(a.y * inv1) << 16);
  u32 p2 = (u32)f2bf(b.x * inv2) | ((u32)f2bf(b.y * inv2) << 16);
  ((u32*)z1q)[(size_t)row * (DIM / 2) + lane] = pq;
  ((u32*)z1c)[(size_t)row * (DIM / 2) + lane] = p1;
  ((u32*)z2c)[(size_t)row * (DIM / 2) + lane] = p2;
  if (lane == 0) pos_sim[row] = dd * inv1 * inv2 * TAU_INV;
}

// ---------------- Kernel B: fused GEMM + sum(2^score) ----------------------
// grid = 1024 : rb = bx&63 (256 q-rows), ch = bx>>6 (16 chunks of 2048 cols)
// ch<8 -> z2c (cross view), ch>=8 -> z1c (intra, diag masked)
// 4 waves/block, each wave: 64 q-rows (4 groups of 16), G=4 A-frag reuse.
// kb-level acc double-buffer: exp(kb-1) overlaps mfma(kb) in the pipes.
__global__ __launch_bounds__(256, 2) void lse_kernel(
    const u16* __restrict__ z1q, const u16* __restrict__ z1c,
    const u16* __restrict__ z2c, float* __restrict__ lparts)
{
  __shared__ __attribute__((aligned(16))) char smem[32768]; // 2 x 64x128 bf16
  const int tid    = threadIdx.x;
  const int lane   = tid & 63, wid = tid >> 6;
  const int rb     = blockIdx.x & 63, ch = blockIdx.x >> 6;
  const int lane15 = lane & 15, laneHi = lane >> 4;
  const int qb     = rb * 256 + wid * 64; // this wave's first q-row

  // Q fragments (B-operand), K1-pre-scaled, register-resident
  bf16x8 qf[4][4];
#pragma unroll
  for (int qg = 0; qg < 4; ++qg)
#pragma unroll
    for (int ks = 0; ks < 4; ++ks)
      qf[qg][ks] = *(const bf16x8*)(z1q + (size_t)(qb + qg * 16 + lane15) * DIM +
                                    ks * 32 + laneHi * 8);

  // column source for this chunk (wave-uniform constant)
  const u16* zt = (ch < 8) ? (z2c + (size_t)ch * 2048 * DIM)
                           : (z1c + (size_t)(ch - 8) * 2048 * DIM);
  int t_diag = -1;
  if (ch >= 8) {
    const int dbase = qb - (ch - 8) * 2048;
    if (dbase >= 0 && dbase < 2048) t_diag = dbase >> 6;
  }

  // staging: LDS linear, global source pre-swizzled with 4-bit row rotation
  // LDS[r][p] holds global[r][p ^ (r&15)] (16B chunks) -> conflict-free reads
  const int gchunk = (tid & 15) ^ ((tid >> 4) & 15);
  const char* const src0 = (const char*)zt + (((tid >> 4) << 8) + (gchunk << 4));
  char* const dst0 = smem + (wid << 10);

  // hoisted per-thread LDS read offsets; cur*16384 + kb*4096 fold into
  // the ds_read 16-bit immediate (max 16384+12288+240+3840 < 64K)
  int aoff[4];
#pragma unroll
  for (int ks = 0; ks < 4; ++ks)
    aoff[ks] = lane15 * 256 + ((((ks << 2) + laneHi) ^ lane15) << 4);

  float lacc[4][4] = {};

  auto stage = [&](int t, int cur) {
    const char* s = src0 + (size_t)t * 16384;
    char* d = dst0 + cur * 16384;
#pragma unroll
    for (int i = 0; i < 4; ++i)
      gload_lds16(s + (i << 12), d + (i << 12));
  };

  auto mfma_kb = [&](int cur, int kb, f32x4 acc[4]) {
    bf16x8 af[4];
#pragma unroll
    for (int ks = 0; ks < 4; ++ks)
      af[ks] = *(const bf16x8*)(smem + aoff[ks] + cur * 16384 + kb * 4096);
#pragma unroll
    for (int qg = 0; qg < 4; ++qg)
      acc[qg] = (f32x4){0.f, 0.f, 0.f, 0.f};
    __builtin_amdgcn_s_setprio(1);
#pragma unroll
    for (int ks = 0; ks < 4; ++ks)
#pragma unroll
      for (int qg = 0; qg < 4; ++qg)
        acc[qg] = __builtin_amdgcn_mfma_f32_16x16x32_bf16(af[ks], qf[qg][ks],
                                                          acc[qg], 0, 0, 0);
    __builtin_amdgcn_s_setprio(0);
  };

  auto exp_kb = [&](int kb, bool dtile, const f32x4 acc[4]) {
    if (!dtile) {
#pragma unroll
      for (int qg = 0; qg < 4; ++qg)
#pragma unroll
        for (int j = 0; j < 4; ++j)
          lacc[qg][j] += EXP2F(acc[qg][j]);
    } else {
#pragma unroll
      for (int qg = 0; qg < 4; ++qg)
#pragma unroll
        for (int j = 0; j < 4; ++j) {
          float v = EXP2F(acc[qg][j]);
          if (kb == qg && (laneHi * 4 + j) == lane15) v = 0.0f;
          lacc[qg][j] += v;
        }
    }
  };

  // software-pipelined tile: exp(kb-1) issues while mfma(kb) is in flight
  auto tile = [&](int cur, bool dtile) {
    f32x4 accA[4], accB[4];
    mfma_kb(cur, 0, accA);
    mfma_kb(cur, 1, accB); exp_kb(0, dtile, accA);
    mfma_kb(cur, 2, accA); exp_kb(1, dtile, accB);
    mfma_kb(cur, 3, accB); exp_kb(2, dtile, accA);
    exp_kb(3, dtile, accB);
  };

  stage(0, 0);
  __syncthreads();
#pragma unroll 1
  for (int tt = 0; tt < 16; ++tt) {
    const int t0 = tt * 2;
    stage(t0 + 1, 1);
    tile(0, t0 == t_diag);
    __syncthreads();
    if (tt < 15) stage(t0 + 2, 0);
    tile(1, t0 + 1 == t_diag);
    __syncthreads();
  }

  // reduce 4 k-partitions (laneHi) per q-row, write partials
#pragma unroll
  for (int qg = 0; qg < 4; ++qg) {
    float l = (lacc[qg][0] + lacc[qg][1]) + (lacc[qg][2] + lacc[qg][3]);
    l += __shfl_xor(l, 16);
    l += __shfl_xor(l, 32);
    if (lane < 16)
      lparts[(size_t)ch * NROWS + qb + qg * 16 + lane15] = l;
  }
}

// ---------------- Kernel C: finalize (32 blocks, atomic into out) ----------
// P_i = sum 2^(K1*cos) = sum exp(s_i) exactly -> lse = ln(P_i), no bias term
__global__ __launch_bounds__(256) void fin_kernel(
    const float* __restrict__ lparts, const float* __restrict__ pos,
    float* __restrict__ out)
{
  __shared__ float red[4];
  const int tid = threadIdx.x, bx = blockIdx.x;
  float s = 0.f;
#pragma unroll 1
  for (int i = bx * 512 + tid; i < (bx + 1) * 512; i += 256) {
    float l = 0.f;
#pragma unroll
    for (int c = 0; c < 16; ++c) l += lparts[(size_t)c * NROWS + i];
    s += logf(l) - pos[i];
  }
#pragma unroll
  for (int d = 1; d < 64; d <<= 1) s += __shfl_xor(s, d);
  if ((tid & 63) == 0) red[tid >> 6] = s;
  __syncthreads();
  if (tid == 0) {
    float t = (red[0] + red[1]) + (red[2] + red[3]);
    atomicAdd(out, t / (float)NROWS);
  }
}

extern "C" void kernel_launch(void* const* d_in, const int* in_sizes, int n_in,
                              void* d_out, int out_size, void* d_ws, size_t ws_size,
                              hipStream_t stream) {
  const float* z1 = (const float*)d_in[0];
  const float* z2 = (const float*)d_in[1];
  float* out = (float*)d_out;
  char* ws = (char*)d_ws;
  const size_t MB4 = (size_t)NROWS * DIM * 2;
  u16* z1q = (u16*)ws;                        // 4 MB (K1-scaled Q)
  u16* z1c = (u16*)(ws + MB4);                // 4 MB (unit, intra cols)
  u16* z2c = (u16*)(ws + 2 * MB4);            // 4 MB (unit, cross cols)
  float* pos = (float*)(ws + 3 * MB4);        // 64 KB
  float* lparts = (float*)(ws + 3 * MB4 + (size_t)NROWS * 4); // 1 MB

  hipMemsetAsync(d_out, 0, sizeof(float), stream);
  hipLaunchKernelGGL(nrm_kernel, dim3(NROWS / 4), dim3(256), 0, stream,
                     z1, z2, z1q, z1c, z2c, pos);
  hipLaunchKernelGGL(lse_kernel, dim3(1024), dim3(256), 0, stream,
                     z1q, z1c, z2c, lparts);
  hipLaunchKernelGGL(fin_kernel, dim3(32), dim3(256), 0, stream,
                     lparts, pos, out);
}

// Round 6
// 184.382 us; speedup vs baseline: 3.5419x; 1.0064x over previous
//
#include <hip/hip_runtime.h>
#include <hip/hip_bf16.h>

#define NROWS 16384
#define DIM 128
#define TAU_INV 14.285714285714285714f
#define K1_CONST 20.6099273650808706f /* log2(e)/tau ; exp(cos/tau) = 2^(K1*cos) */

typedef __attribute__((ext_vector_type(8))) __bf16 bf16x8;
typedef __attribute__((ext_vector_type(4))) float f32x4;
typedef unsigned int u32;
typedef unsigned short u16;

#if __has_builtin(__builtin_amdgcn_exp2f)
#define EXP2F(x) __builtin_amdgcn_exp2f(x)
#else
#define EXP2F(x) exp2f(x)
#endif

__device__ __forceinline__ u16 f2bf(float x) {
  __hip_bfloat16 h = __float2bfloat16(x);
  return *reinterpret_cast<u16*>(&h);
}

__device__ __forceinline__ void gload_lds16(const void* g, void* l) {
  __builtin_amdgcn_global_load_lds(
      (const __attribute__((address_space(1))) u32*)g,
      (__attribute__((address_space(3))) u32*)l, 16, 0, 0);
}

// ------- Kernel A: normalize -> z1q (K1-scaled Q), z1c/z2c (unit), pos -----
__global__ __launch_bounds__(256) void nrm_kernel(
    const float* __restrict__ z1, const float* __restrict__ z2,
    u16* __restrict__ z1q, u16* __restrict__ z1c, u16* __restrict__ z2c,
    float* __restrict__ pos_sim)
{
  const int tid  = threadIdx.x;
  const int lane = tid & 63, wid = tid >> 6;
  const int row  = blockIdx.x * 4 + wid;
  const float2 a = *(const float2*)(z1 + (size_t)row * DIM + lane * 2);
  const float2 b = *(const float2*)(z2 + (size_t)row * DIM + lane * 2);
  float ss1 = a.x * a.x + a.y * a.y;
  float ss2 = b.x * b.x + b.y * b.y;
  float dd  = a.x * b.x + a.y * b.y;
#pragma unroll
  for (int d = 1; d < 64; d <<= 1) {
    ss1 += __shfl_xor(ss1, d);
    ss2 += __shfl_xor(ss2, d);
    dd  += __shfl_xor(dd,  d);
  }
  const float inv1 = 1.0f / fmaxf(sqrtf(ss1), 1e-12f);
  const float inv2 = 1.0f / fmaxf(sqrtf(ss2), 1e-12f);
  const float s1q = inv1 * K1_CONST;
  u32 pq = (u32)f2bf(a.x * s1q) | ((u32)f2bf(a.y * s1q) << 16);
  u32 p1 = (u32)f2bf(a.x * inv1) | ((u32)f2bf(a.y * inv1) << 16);
  u32 p2 = (u32)f2bf(b.x * inv2) | ((u32)f2bf(b.y * inv2) << 16);
  ((u32*)z1q)[(size_t)row * (DIM / 2) + lane] = pq;
  ((u32*)z1c)[(size_t)row * (DIM / 2) + lane] = p1;
  ((u32*)z2c)[(size_t)row * (DIM / 2) + lane] = p2;
  if (lane == 0) pos_sim[row] = dd * inv1 * inv2 * TAU_INV;
}

// ---------------- Kernel B: fused GEMM + sum(2^score) ----------------------
// grid = 1024 : rb = bx&63 (256 q-rows), ch = bx>>6 (16 chunks of 2048 cols)
// ch<8 -> z2c (cross view), ch>=8 -> z1c (intra, diag masked)
// 4 waves/block, each wave: 64 q-rows (4 groups of 16), G=4 A-frag reuse.
// T3/T4 pipeline: 3 LDS buffers, stage tile t+2 during tile t (1 chunk per
// kb-phase); tile-end sync = counted s_waitcnt vmcnt(4) + raw s_barrier
// (never drain vmcnt to 0 in-loop). __syncthreads()'s implicit vmcnt(0)
// drain was the structural stall in rounds 1-5.
__global__ __launch_bounds__(256, 2) void lse_kernel(
    const u16* __restrict__ z1q, const u16* __restrict__ z1c,
    const u16* __restrict__ z2c, float* __restrict__ lparts)
{
  __shared__ __attribute__((aligned(16))) char smem[49152]; // 3 x 64x128 bf16
  const int tid    = threadIdx.x;
  const int lane   = tid & 63, wid = tid >> 6;
  const int rb     = blockIdx.x & 63, ch = blockIdx.x >> 6;
  const int lane15 = lane & 15, laneHi = lane >> 4;
  const int qb     = rb * 256 + wid * 64; // this wave's first q-row

  // Q fragments (B-operand), K1-pre-scaled, register-resident
  bf16x8 qf[4][4];
#pragma unroll
  for (int qg = 0; qg < 4; ++qg)
#pragma unroll
    for (int ks = 0; ks < 4; ++ks)
      qf[qg][ks] = *(const bf16x8*)(z1q + (size_t)(qb + qg * 16 + lane15) * DIM +
                                    ks * 32 + laneHi * 8);

  // column source for this chunk (wave-uniform constant)
  const u16* zt = (ch < 8) ? (z2c + (size_t)ch * 2048 * DIM)
                           : (z1c + (size_t)(ch - 8) * 2048 * DIM);
  int t_diag = -1;
  if (ch >= 8) {
    const int dbase = qb - (ch - 8) * 2048;
    if (dbase >= 0 && dbase < 2048) t_diag = dbase >> 6;
  }

  // staging: LDS linear, global source pre-swizzled with 4-bit row rotation
  // LDS[r][p] holds global[r][p ^ (r&15)] (16B chunks) -> conflict-free reads
  const int gchunk = (tid & 15) ^ ((tid >> 4) & 15);
  const char* const src0 = (const char*)zt + (((tid >> 4) << 8) + (gchunk << 4));
  char* const dst0 = smem + (wid << 10);

  // hoisted per-thread LDS read offsets; kb*4096 folds into ds_read immediate
  int aoff[4];
#pragma unroll
  for (int ks = 0; ks < 4; ++ks)
    aoff[ks] = lane15 * 256 + ((((ks << 2) + laneHi) ^ lane15) << 4);

  float lacc[4][4] = {};

  auto stage_chunk = [&](int t, int i) { // tile t, quarter i -> buf (t%3)
    gload_lds16(src0 + (size_t)t * 16384 + (i << 12),
                dst0 + (t % 3) * 16384 + (i << 12));
  };

  auto mfma_kb = [&](int bufo, int kb, f32x4 acc[4]) {
    bf16x8 af[4];
#pragma unroll
    for (int ks = 0; ks < 4; ++ks)
      af[ks] = *(const bf16x8*)(smem + aoff[ks] + bufo + kb * 4096);
#pragma unroll
    for (int qg = 0; qg < 4; ++qg)
      acc[qg] = (f32x4){0.f, 0.f, 0.f, 0.f};
    __builtin_amdgcn_s_setprio(1);
#pragma unroll
    for (int ks = 0; ks < 4; ++ks)
#pragma unroll
      for (int qg = 0; qg < 4; ++qg)
        acc[qg] = __builtin_amdgcn_mfma_f32_16x16x32_bf16(af[ks], qf[qg][ks],
                                                          acc[qg], 0, 0, 0);
    __builtin_amdgcn_s_setprio(0);
  };

  auto exp_kb = [&](int kb, bool dtile, const f32x4 acc[4]) {
    if (!dtile) {
#pragma unroll
      for (int qg = 0; qg < 4; ++qg)
#pragma unroll
        for (int j = 0; j < 4; ++j)
          lacc[qg][j] += EXP2F(acc[qg][j]);
    } else {
#pragma unroll
      for (int qg = 0; qg < 4; ++qg)
#pragma unroll
        for (int j = 0; j < 4; ++j) {
          float v = EXP2F(acc[qg][j]);
          if (kb == qg && (laneHi * 4 + j) == lane15) v = 0.0f;
          lacc[qg][j] += v;
        }
    }
  };

  // prologue: stage tiles 0 and 1; wait tile 0 only (vmcnt(4) = allow tile 1)
#pragma unroll
  for (int i = 0; i < 4; ++i) stage_chunk(0, i);
#pragma unroll
  for (int i = 0; i < 4; ++i) stage_chunk(1, i);
  asm volatile("s_waitcnt vmcnt(4)" ::: "memory");
  __builtin_amdgcn_s_barrier();
  __builtin_amdgcn_sched_barrier(0);

#pragma unroll 1
  for (int t = 0; t < 32; ++t) {
    const int bufo = (t % 3) * 16384;
    const bool dt  = (t == t_diag);
    const bool pre = (t + 2 < 32);
    f32x4 accA[4], accB[4];
    if (pre) stage_chunk(t + 2, 0);
    mfma_kb(bufo, 0, accA);
    if (pre) stage_chunk(t + 2, 1);
    mfma_kb(bufo, 1, accB); exp_kb(0, dt, accA);
    if (pre) stage_chunk(t + 2, 2);
    mfma_kb(bufo, 2, accA); exp_kb(1, dt, accB);
    if (pre) stage_chunk(t + 2, 3);
    mfma_kb(bufo, 3, accB); exp_kb(2, dt, accA);
    exp_kb(3, dt, accB);
    // counted sync: t+1's loads (issued at t-1) forced done; t+2's may fly
    if (t < 30) asm volatile("s_waitcnt vmcnt(4)" ::: "memory");
    else        asm volatile("s_waitcnt vmcnt(0)" ::: "memory");
    if (t < 31) __builtin_amdgcn_s_barrier();
    __builtin_amdgcn_sched_barrier(0);
  }

  // reduce 4 k-partitions (laneHi) per q-row, write partials
#pragma unroll
  for (int qg = 0; qg < 4; ++qg) {
    float l = (lacc[qg][0] + lacc[qg][1]) + (lacc[qg][2] + lacc[qg][3]);
    l += __shfl_xor(l, 16);
    l += __shfl_xor(l, 32);
    if (lane < 16)
      lparts[(size_t)ch * NROWS + qb + qg * 16 + lane15] = l;
  }
}

// ---------------- Kernel C: finalize (32 blocks, atomic into out) ----------
// P_i = sum 2^(K1*cos) = sum exp(s_i) exactly -> lse = ln(P_i), no bias term
__global__ __launch_bounds__(256) void fin_kernel(
    const float* __restrict__ lparts, const float* __restrict__ pos,
    float* __restrict__ out)
{
  __shared__ float red[4];
  const int tid = threadIdx.x, bx = blockIdx.x;
  float s = 0.f;
#pragma unroll 1
  for (int i = bx * 512 + tid; i < (bx + 1) * 512; i += 256) {
    float l = 0.f;
#pragma unroll
    for (int c = 0; c < 16; ++c) l += lparts[(size_t)c * NROWS + i];
    s += logf(l) - pos[i];
  }
#pragma unroll
  for (int d = 1; d < 64; d <<= 1) s += __shfl_xor(s, d);
  if ((tid & 63) == 0) red[tid >> 6] = s;
  __syncthreads();
  if (tid == 0) {
    float t = (red[0] + red[1]) + (red[2] + red[3]);
    atomicAdd(out, t / (float)NROWS);
  }
}

extern "C" void kernel_launch(void* const* d_in, const int* in_sizes, int n_in,
                              void* d_out, int out_size, void* d_ws, size_t ws_size,
                              hipStream_t stream) {
  const float* z1 = (const float*)d_in[0];
  const float* z2 = (const float*)d_in[1];
  float* out = (float*)d_out;
  char* ws = (char*)d_ws;
  const size_t MB4 = (size_t)NROWS * DIM * 2;
  u16* z1q = (u16*)ws;                        // 4 MB (K1-scaled Q)
  u16* z1c = (u16*)(ws + MB4);                // 4 MB (unit, intra cols)
  u16* z2c = (u16*)(ws + 2 * MB4);            // 4 MB (unit, cross cols)
  float* pos = (float*)(ws + 3 * MB4);        // 64 KB
  float* lparts = (float*)(ws + 3 * MB4 + (size_t)NROWS * 4); // 1 MB

  hipMemsetAsync(d_out, 0, sizeof(float), stream);
  hipLaunchKernelGGL(nrm_kernel, dim3(NROWS / 4), dim3(256), 0, stream,
                     z1, z2, z1q, z1c, z2c, pos);
  hipLaunchKernelGGL(lse_kernel, dim3(1024), dim3(256), 0, stream,
                     z1q, z1c, z2c, lparts);
  hipLaunchKernelGGL(fin_kernel, dim3(32), dim3(256), 0, stream,
                     lparts, pos, out);
}